// Round 2
// baseline (637.098 us; speedup 1.0000x reference)
//
#include <hip/hip_runtime.h>
#include <stdint.h>

// Problem constants (fixed by the reference setup)
#define M_DIM 4
#define K_DIM 8192
#define N_DIM 28672
#define GRP 128                       // quant group size along K
#define KK_TOTAL (K_DIM / 2)          // 4096 packed rows
#define KK_PER_GRP (GRP / 2)          // 64 packed rows per group
#define N_GROUPS (K_DIM / GRP)        // 64 groups
#define BLOCK 256
#define COLS_PER_THREAD 4
#define COLS_PER_BLOCK (BLOCK * COLS_PER_THREAD)   // 1024
#define NBLK (N_DIM / COLS_PER_BLOCK)              // 28

// NOTE on dtypes: the reference is jnp.float16, which the harness stages as
// float32 ("else float*" rule) for x/scales/bias and expects float32 output.
// weight_packed is int32 (one payload byte per element).

// Main kernel: each block handles gps groups (64 packed kk-rows each) x 1024
// columns. Writes f32 partial sums to ws[split][M][N].
__global__ __launch_bounds__(BLOCK) void int4_gemv_main(
    const float* __restrict__ x,        // [M][K] f32
    const int*   __restrict__ wp,       // [KK_TOTAL][N] packed bytes in int32
    const float* __restrict__ scales,   // [N_GROUPS][N] f32
    float*       __restrict__ ws,       // [splits][M][N] f32 partials
    int gps)                            // groups per split
{
    __shared__ float xs[GRP * M_DIM];   // xs[j*4+m] = x[m][g*GRP+j]

    const int tid   = threadIdx.x;
    const int nb    = blockIdx.x;
    const int split = blockIdx.y;
    const int g0    = split * gps;
    const int n0    = nb * COLS_PER_BLOCK + tid * COLS_PER_THREAD;

    float acc[M_DIM][COLS_PER_THREAD];
    #pragma unroll
    for (int m = 0; m < M_DIM; m++)
        #pragma unroll
        for (int c = 0; c < COLS_PER_THREAD; c++) acc[m][c] = 0.f;

    for (int gi = 0; gi < gps; gi++) {
        const int g = g0 + gi;

        // Stage this group's x slice into LDS (512 floats), interleaved by m.
        __syncthreads();  // protect xs from readers of previous group
        for (int e = tid; e < GRP * M_DIM; e += BLOCK) {
            const int m = e & 3;
            const int j = e >> 2;
            xs[e] = x[m * K_DIM + g * GRP + j];
        }
        __syncthreads();

        // Group scales for this thread's 4 columns (16B-aligned float4)
        const float4 sv = *(const float4*)(scales + (size_t)g * N_DIM + n0);
        const float s[COLS_PER_THREAD] = {sv.x, sv.y, sv.z, sv.w};

        float accg[M_DIM][COLS_PER_THREAD];
        #pragma unroll
        for (int m = 0; m < M_DIM; m++)
            #pragma unroll
            for (int c = 0; c < COLS_PER_THREAD; c++) accg[m][c] = 0.f;

        const int* wrow = wp + (size_t)(g * KK_PER_GRP) * N_DIM + n0;

        #pragma unroll 4
        for (int kkl = 0; kkl < KK_PER_GRP; kkl++) {
            const int4 w4 = *(const int4*)(wrow + (size_t)kkl * N_DIM);

            // Uniform (broadcast) LDS reads: x for k=2*kk (lo) and 2*kk+1 (hi)
            float xl[M_DIM], xh[M_DIM];
            #pragma unroll
            for (int m = 0; m < M_DIM; m++) {
                xl[m] = xs[(2 * kkl) * M_DIM + m];
                xh[m] = xs[(2 * kkl + 1) * M_DIM + m];
            }

            const int wv[4] = {w4.x, w4.y, w4.z, w4.w};
            #pragma unroll
            for (int c = 0; c < COLS_PER_THREAD; c++) {
                const float lo = (float)(wv[c] & 0xF) - 8.0f;
                const float hi = (float)((wv[c] >> 4) & 0xF) - 8.0f;
                #pragma unroll
                for (int m = 0; m < M_DIM; m++) {
                    accg[m][c] = fmaf(xl[m], lo, accg[m][c]);
                    accg[m][c] = fmaf(xh[m], hi, accg[m][c]);
                }
            }
        }

        // Apply group scale once per group
        #pragma unroll
        for (int m = 0; m < M_DIM; m++)
            #pragma unroll
            for (int c = 0; c < COLS_PER_THREAD; c++)
                acc[m][c] = fmaf(accg[m][c], s[c], acc[m][c]);
    }

    // Write f32 partials (coalesced float4)
    float* wsp = ws + (size_t)split * (M_DIM * N_DIM);
    #pragma unroll
    for (int m = 0; m < M_DIM; m++) {
        float4 v = make_float4(acc[m][0], acc[m][1], acc[m][2], acc[m][3]);
        *(float4*)(wsp + (size_t)m * N_DIM + n0) = v;
    }
}

// Reduction: out[m][n] = sum_s ws[s][m][n] + bias[n], f32 out.
__global__ __launch_bounds__(256) void int4_gemv_reduce(
    const float* __restrict__ ws,
    const float* __restrict__ bias,
    float*       __restrict__ out,
    int splits)
{
    const int idx = blockIdx.x * 256 + threadIdx.x;  // over M*N
    if (idx >= M_DIM * N_DIM) return;
    const int n = idx % N_DIM;
    float a = bias[n];
    for (int s = 0; s < splits; s++)
        a += ws[(size_t)s * (M_DIM * N_DIM) + idx];
    out[idx] = a;
}

extern "C" void kernel_launch(void* const* d_in, const int* in_sizes, int n_in,
                              void* d_out, int out_size, void* d_ws, size_t ws_size,
                              hipStream_t stream) {
    const float* x      = (const float*)d_in[0];   // [4][8192] f32
    const int*   wpk    = (const int*)d_in[1];     // [4096][28672] int32
    const float* scales = (const float*)d_in[2];   // [64][28672] f32
    const float* bias   = (const float*)d_in[3];   // [28672] f32
    // d_in[4] = group_size scalar (=128), baked into constants

    float* out = (float*)d_out;
    float* ws  = (float*)d_ws;

    // Pick the largest split-K that fits the workspace (default 64 -> ~29 MB).
    int splits = N_GROUPS;  // 64
    while (splits > 1 &&
           (size_t)splits * (size_t)(M_DIM * N_DIM) * sizeof(float) > ws_size)
        splits >>= 1;
    const int gps = N_GROUPS / splits;

    dim3 grid(NBLK, splits);
    int4_gemv_main<<<grid, BLOCK, 0, stream>>>(x, wpk, scales, ws, gps);

    const int total = M_DIM * N_DIM;
    int4_gemv_reduce<<<(total + 255) / 256, 256, 0, stream>>>(ws, bias, out, splits);
}

// Round 3
// 630.812 us; speedup vs baseline: 1.0100x; 1.0100x over previous
//
#include <hip/hip_runtime.h>
#include <stdint.h>

// Problem constants (fixed by the reference setup)
#define M_DIM 4
#define K_DIM 8192
#define N_DIM 28672
#define GRP 128                         // quant group size along K
#define KK_PER_GRP (GRP / 2)            // 64 packed rows per group
#define N_GROUPS (K_DIM / GRP)          // 64 groups
#define BLOCK 256

// ---- fast path: one quant group per block, 8 cols/thread ----
#define CPT 8
#define COLS_PER_BLOCK (BLOCK * CPT)            // 2048
#define NBLK_FAST (N_DIM / COLS_PER_BLOCK)      // 14
#define PF 4                                    // prefetch pipeline depth (rows)

// dtypes: reference is jnp.float16 -> harness stages x/scales/bias as float32
// and expects float32 output. weight_packed is int32 (one payload byte each).

__global__ __launch_bounds__(BLOCK, 4) void int4_gemv_fast(
    const float* __restrict__ x,        // [M][K] f32
    const int*   __restrict__ wp,       // [K/2][N] packed bytes in int32
    const float* __restrict__ scales,   // [N_GROUPS][N] f32
    float*       __restrict__ ws)       // [N_GROUPS][M][N] f32 partials
{
    __shared__ float xs[GRP * M_DIM];   // xs[j*4+m] = x[m][g*128+j]

    const int tid = threadIdx.x;
    const int g   = blockIdx.y;                           // group == split
    const int n0  = blockIdx.x * COLS_PER_BLOCK + tid * CPT;

    // Stage this group's x slice (512 floats), coalesced reads.
    #pragma unroll
    for (int e = tid; e < GRP * M_DIM; e += BLOCK) {      // 2 iterations
        const int m = e >> 7;                             // 0..3
        const int j = e & 127;
        xs[j * M_DIM + m] = x[m * K_DIM + g * GRP + j];
    }
    __syncthreads();

    float acc[M_DIM][CPT];
    #pragma unroll
    for (int m = 0; m < M_DIM; m++)
        #pragma unroll
        for (int c = 0; c < CPT; c++) acc[m][c] = 0.f;

    const int* wrow = wp + (size_t)g * KK_PER_GRP * N_DIM + n0;

    // Depth-PF software pipeline: keep 2*PF 16B loads in flight per lane.
    int4 bufA[PF], bufB[PF];
    #pragma unroll
    for (int i = 0; i < PF; i++) {
        bufA[i] = *(const int4*)(wrow + (size_t)i * N_DIM);
        bufB[i] = *(const int4*)(wrow + (size_t)i * N_DIM + 4);
    }

    #pragma unroll 4
    for (int kk = 0; kk < KK_PER_GRP; kk++) {
        const int cur = kk & (PF - 1);
        const int4 wa = bufA[cur];
        const int4 wb = bufB[cur];
        if (kk + PF < KK_PER_GRP) {   // uniform; prefetch PF rows ahead
            bufA[cur] = *(const int4*)(wrow + (size_t)(kk + PF) * N_DIM);
            bufB[cur] = *(const int4*)(wrow + (size_t)(kk + PF) * N_DIM + 4);
        }

        // Broadcast LDS reads: x[m][2kk] and x[m][2kk+1] for all m.
        const float4 xlo = *(const float4*)&xs[(2 * kk) * M_DIM];
        const float4 xhi = *(const float4*)&xs[(2 * kk + 1) * M_DIM];

        const int wv[CPT] = {wa.x, wa.y, wa.z, wa.w, wb.x, wb.y, wb.z, wb.w};
        #pragma unroll
        for (int c = 0; c < CPT; c++) {
            const float lo = (float)(wv[c] & 0xF) - 8.0f;   // byte value 0..255
            const float hi = (float)(wv[c] >> 4) - 8.0f;    // >>4 of 0..255 -> 0..15
            acc[0][c] = fmaf(xlo.x, lo, acc[0][c]);
            acc[1][c] = fmaf(xlo.y, lo, acc[1][c]);
            acc[2][c] = fmaf(xlo.z, lo, acc[2][c]);
            acc[3][c] = fmaf(xlo.w, lo, acc[3][c]);
            acc[0][c] = fmaf(xhi.x, hi, acc[0][c]);
            acc[1][c] = fmaf(xhi.y, hi, acc[1][c]);
            acc[2][c] = fmaf(xhi.z, hi, acc[2][c]);
            acc[3][c] = fmaf(xhi.w, hi, acc[3][c]);
        }
    }

    // Epilogue: apply group scale, write f32 partials (two float4 per m).
    const float4 s0 = *(const float4*)(scales + (size_t)g * N_DIM + n0);
    const float4 s1 = *(const float4*)(scales + (size_t)g * N_DIM + n0 + 4);
    const float sc[CPT] = {s0.x, s0.y, s0.z, s0.w, s1.x, s1.y, s1.z, s1.w};

    float* wsp = ws + (size_t)g * (M_DIM * N_DIM);
    #pragma unroll
    for (int m = 0; m < M_DIM; m++) {
        float4 o0 = make_float4(acc[m][0] * sc[0], acc[m][1] * sc[1],
                                acc[m][2] * sc[2], acc[m][3] * sc[3]);
        float4 o1 = make_float4(acc[m][4] * sc[4], acc[m][5] * sc[5],
                                acc[m][6] * sc[6], acc[m][7] * sc[7]);
        *(float4*)(wsp + (size_t)m * N_DIM + n0)     = o0;
        *(float4*)(wsp + (size_t)m * N_DIM + n0 + 4) = o1;
    }
}

// Reduce 64 partials + bias, float4-vectorized. out[m][n] f32.
__global__ __launch_bounds__(256) void int4_gemv_reduce64(
    const float* __restrict__ ws,
    const float* __restrict__ bias,
    float*       __restrict__ out)
{
    const int mn = (blockIdx.x * 256 + threadIdx.x) * 4;  // over M*N
    if (mn >= M_DIM * N_DIM) return;
    const int n = mn % N_DIM;   // N_DIM % 4 == 0 so float4-aligned
    float4 a = *(const float4*)(bias + n);
    #pragma unroll 8
    for (int s = 0; s < N_GROUPS; s++) {
        const float4 v = *(const float4*)(ws + (size_t)s * (M_DIM * N_DIM) + mn);
        a.x += v.x; a.y += v.y; a.z += v.z; a.w += v.w;
    }
    *(float4*)(out + mn) = a;
}

// ---------------- generic fallback (R2 kernel) for tiny ws ----------------
#define G_CPT 4
#define G_COLS_PER_BLOCK (BLOCK * G_CPT)
#define G_NBLK (N_DIM / G_COLS_PER_BLOCK)

__global__ __launch_bounds__(BLOCK) void int4_gemv_generic(
    const float* __restrict__ x, const int* __restrict__ wp,
    const float* __restrict__ scales, float* __restrict__ ws, int gps)
{
    __shared__ float xs[GRP * M_DIM];
    const int tid = threadIdx.x;
    const int split = blockIdx.y;
    const int g0 = split * gps;
    const int n0 = blockIdx.x * G_COLS_PER_BLOCK + tid * G_CPT;

    float acc[M_DIM][G_CPT];
    #pragma unroll
    for (int m = 0; m < M_DIM; m++)
        #pragma unroll
        for (int c = 0; c < G_CPT; c++) acc[m][c] = 0.f;

    for (int gi = 0; gi < gps; gi++) {
        const int g = g0 + gi;
        __syncthreads();
        for (int e = tid; e < GRP * M_DIM; e += BLOCK) {
            const int m = e & 3, j = e >> 2;
            xs[e] = x[m * K_DIM + g * GRP + j];
        }
        __syncthreads();
        const float4 sv = *(const float4*)(scales + (size_t)g * N_DIM + n0);
        const float s[G_CPT] = {sv.x, sv.y, sv.z, sv.w};
        float accg[M_DIM][G_CPT];
        #pragma unroll
        for (int m = 0; m < M_DIM; m++)
            #pragma unroll
            for (int c = 0; c < G_CPT; c++) accg[m][c] = 0.f;
        const int* wrow = wp + (size_t)(g * KK_PER_GRP) * N_DIM + n0;
        #pragma unroll 4
        for (int kkl = 0; kkl < KK_PER_GRP; kkl++) {
            const int4 w4 = *(const int4*)(wrow + (size_t)kkl * N_DIM);
            float xl[M_DIM], xh[M_DIM];
            #pragma unroll
            for (int m = 0; m < M_DIM; m++) {
                xl[m] = xs[(2 * kkl) * M_DIM + m];
                xh[m] = xs[(2 * kkl + 1) * M_DIM + m];
            }
            const int wv[4] = {w4.x, w4.y, w4.z, w4.w};
            #pragma unroll
            for (int c = 0; c < G_CPT; c++) {
                const float lo = (float)(wv[c] & 0xF) - 8.0f;
                const float hi = (float)(wv[c] >> 4) - 8.0f;
                #pragma unroll
                for (int m = 0; m < M_DIM; m++) {
                    accg[m][c] = fmaf(xl[m], lo, accg[m][c]);
                    accg[m][c] = fmaf(xh[m], hi, accg[m][c]);
                }
            }
        }
        #pragma unroll
        for (int m = 0; m < M_DIM; m++)
            #pragma unroll
            for (int c = 0; c < G_CPT; c++)
                acc[m][c] = fmaf(accg[m][c], s[c], acc[m][c]);
    }
    float* wsp = ws + (size_t)split * (M_DIM * N_DIM);
    #pragma unroll
    for (int m = 0; m < M_DIM; m++)
        *(float4*)(wsp + (size_t)m * N_DIM + n0) =
            make_float4(acc[m][0], acc[m][1], acc[m][2], acc[m][3]);
}

__global__ __launch_bounds__(256) void int4_gemv_reduce_generic(
    const float* __restrict__ ws, const float* __restrict__ bias,
    float* __restrict__ out, int splits)
{
    const int idx = blockIdx.x * 256 + threadIdx.x;
    if (idx >= M_DIM * N_DIM) return;
    const int n = idx % N_DIM;
    float a = bias[n];
    for (int s = 0; s < splits; s++)
        a += ws[(size_t)s * (M_DIM * N_DIM) + idx];
    out[idx] = a;
}

extern "C" void kernel_launch(void* const* d_in, const int* in_sizes, int n_in,
                              void* d_out, int out_size, void* d_ws, size_t ws_size,
                              hipStream_t stream) {
    const float* x      = (const float*)d_in[0];   // [4][8192] f32
    const int*   wpk    = (const int*)d_in[1];     // [4096][28672] int32
    const float* scales = (const float*)d_in[2];   // [64][28672] f32
    const float* bias   = (const float*)d_in[3];   // [28672] f32
    float* out = (float*)d_out;
    float* ws  = (float*)d_ws;

    const size_t need = (size_t)N_GROUPS * (M_DIM * N_DIM) * sizeof(float);
    if (ws_size >= need) {
        dim3 grid(NBLK_FAST, N_GROUPS);   // 14 x 64 = 896 blocks, all resident
        int4_gemv_fast<<<grid, BLOCK, 0, stream>>>(x, wpk, scales, ws);
        int4_gemv_reduce64<<<(M_DIM * N_DIM / 4 + 255) / 256, 256, 0, stream>>>(
            ws, bias, out);
    } else {
        int splits = N_GROUPS;
        while (splits > 1 &&
               (size_t)splits * (size_t)(M_DIM * N_DIM) * sizeof(float) > ws_size)
            splits >>= 1;
        const int gps = N_GROUPS / splits;
        dim3 grid(G_NBLK, splits);
        int4_gemv_generic<<<grid, BLOCK, 0, stream>>>(x, wpk, scales, ws, gps);
        int4_gemv_reduce_generic<<<(M_DIM * N_DIM + 255) / 256, 256, 0, stream>>>(
            ws, bias, out, splits);
    }
}